// Round 4
// baseline (356.739 us; speedup 1.0000x reference)
//
#include <hip/hip_runtime.h>
#include <hip/hip_bf16.h>
#include <math.h>

#define THREADS 256
typedef unsigned short ushortT;
typedef __attribute__((ext_vector_type(8))) short bf16x8;   // 8 bf16 = 4 VGPRs
typedef __attribute__((ext_vector_type(4))) float f32x4;

__device__ __forceinline__ ushortT f2bf(float f) {
  __hip_bfloat16 h = __float2bfloat16(f);
  return *reinterpret_cast<ushortT*>(&h);
}

// ---------------------------------------------------------------------------
// Kernel A: fused L2-norm + bf16 convert. One block per row (256 thr x float4).
// ---------------------------------------------------------------------------
__global__ __launch_bounds__(THREADS) void k_prep(const float* __restrict__ x,
                                                  ushortT* __restrict__ xn, int D) {
  __shared__ float red[4];
  const int row = blockIdx.x;
  const int tid = threadIdx.x;
  const int gid = row * (D / 4) + tid;
  const float4 v = reinterpret_cast<const float4*>(x)[gid];
  float s = v.x * v.x + v.y * v.y + v.z * v.z + v.w * v.w;
  #pragma unroll
  for (int off = 32; off; off >>= 1) s += __shfl_xor(s, off);
  if ((tid & 63) == 0) red[tid >> 6] = s;
  __syncthreads();
  const float tot = red[0] + red[1] + red[2] + red[3];
  const float rn = 1.0f / fmaxf(sqrtf(tot), 1e-12f);
  ushort4 o;
  o.x = f2bf(v.x * rn); o.y = f2bf(v.y * rn);
  o.z = f2bf(v.z * rn); o.w = f2bf(v.w * rn);
  reinterpret_cast<ushort4*>(xn)[gid] = o;
}

// ---------------------------------------------------------------------------
// Kernel B: barrier-free wave-private 64x64x1024 MFMA tiles, fragments loaded
// DIRECTLY from global (no LDS, no __syncthreads in the K-loop). The 16x16x32
// A/B fragment is 16 contiguous bytes at xn[row*D + k] -> global_load_dwordx4
// per lane, register double-buffered; the compiler emits fine-grained vmcnt
// waits instead of the structural vmcnt(0)+s_barrier drain of the LDS path.
// Triangular wave-tile decode (8256 tiles over 128x128 blocks of 64), dual-
// orientation circle-loss epilogue (row partials for both the i-rows and,
// via symmetry, the j-rows). partial[row*128 + cb] = {mp, sp, 0, sn}, each
// (row, cb) written exactly once.
// ---------------------------------------------------------------------------
__global__ __launch_bounds__(THREADS, 2) void k_main_mfma(const ushortT* __restrict__ xn,
                                                          const int* __restrict__ tgt,
                                                          float4* __restrict__ partial,
                                                          int D, int nb) {
  const int tid = threadIdx.x;
  const int lane = tid & 63;
  const int w = tid >> 6;

  // --- triangular decode: wave-tile t -> (bi <= bj) in 64-row block units
  const int t = blockIdx.x * 4 + w;
  int bi = (int)((2.f * nb + 1.f -
                  sqrtf((2.f * nb + 1.f) * (2.f * nb + 1.f) - 8.f * (float)t)) * 0.5f);
  while ((bi + 1) * (2 * nb - bi) / 2 <= t) ++bi;
  while (bi * (2 * nb - bi + 1) / 2 > t) --bi;
  const int bj = bi + (t - bi * (2 * nb - bi + 1) / 2);
  const bool isdiag = (bi == bj);

  const int i0 = bi * 64, j0 = bj * 64;
  const int c = lane & 15;      // fragment row-within-16 / output col
  const int q = lane >> 4;      // k-chunk 0..3 (k = q*8 + j)

  // --- fragment base addresses: frag(mt,kk) = 16B at (i0+mt*16+c)*D + kk*32 + q*8
  const ushortT* aB = xn + (size_t)(i0 + c) * D + q * 8;
  const ushortT* bB = xn + (size_t)(j0 + c) * D + q * 8;

  f32x4 acc[4][4];
  #pragma unroll
  for (int mt = 0; mt < 4; ++mt)
    #pragma unroll
    for (int nt = 0; nt < 4; ++nt)
      acc[mt][nt] = (f32x4){0.f, 0.f, 0.f, 0.f};

  bf16x8 a0[4], b0[4], a1[4], b1[4];
  const size_t rstep = (size_t)16 * D;

  #pragma unroll
  for (int mt = 0; mt < 4; ++mt) {
    a0[mt] = *reinterpret_cast<const bf16x8*>(aB + mt * rstep);
    b0[mt] = *reinterpret_cast<const bf16x8*>(bB + mt * rstep);
  }

  const int kiters = D / 32;  // 32
  #pragma unroll 4
  for (int kk = 0; kk < kiters; kk += 2) {
    const size_t o1 = (size_t)(kk + 1) * 32;
    #pragma unroll
    for (int mt = 0; mt < 4; ++mt) {
      a1[mt] = *reinterpret_cast<const bf16x8*>(aB + o1 + mt * rstep);
      b1[mt] = *reinterpret_cast<const bf16x8*>(bB + o1 + mt * rstep);
    }
    #pragma unroll
    for (int mt = 0; mt < 4; ++mt)
      #pragma unroll
      for (int nt = 0; nt < 4; ++nt)
        acc[mt][nt] = __builtin_amdgcn_mfma_f32_16x16x32_bf16(a0[mt], b0[nt], acc[mt][nt], 0, 0, 0);
    if (kk + 2 < kiters) {
      const size_t o2 = (size_t)(kk + 2) * 32;
      #pragma unroll
      for (int mt = 0; mt < 4; ++mt) {
        a0[mt] = *reinterpret_cast<const bf16x8*>(aB + o2 + mt * rstep);
        b0[mt] = *reinterpret_cast<const bf16x8*>(bB + o2 + mt * rstep);
      }
    }
    #pragma unroll
    for (int mt = 0; mt < 4; ++mt)
      #pragma unroll
      for (int nt = 0; nt < 4; ++nt)
        acc[mt][nt] = __builtin_amdgcn_mfma_f32_16x16x32_bf16(a1[mt], b1[nt], acc[mt][nt], 0, 0, 0);
  }

  // --- epilogue. C/D layout: col = lane&15, row = (lane>>4)*4 + reg
  int tj[4];
  #pragma unroll
  for (int nt = 0; nt < 4; ++nt) tj[nt] = tgt[j0 + nt * 16 + c];
  int tir[16];
  #pragma unroll
  for (int mt = 0; mt < 4; ++mt) {
    const int4 t4 = *reinterpret_cast<const int4*>(tgt + i0 + mt * 16 + q * 4);
    tir[mt * 4 + 0] = t4.x; tir[mt * 4 + 1] = t4.y;
    tir[mt * 4 + 2] = t4.z; tir[mt * 4 + 3] = t4.w;
  }

  // orientation 1: rows of bi block, cols of bj block
  #pragma unroll
  for (int mt = 0; mt < 4; ++mt) {
    #pragma unroll
    for (int reg = 0; reg < 4; ++reg) {
      const int i = i0 + mt * 16 + q * 4 + reg;
      const int ti = tir[mt * 4 + reg];
      float m = -1e30f, sn = 0.f;
      float sel[4];
      #pragma unroll
      for (int nt = 0; nt < 4; ++nt) {
        const float s = acc[mt][nt][reg];
        const int j = j0 + nt * 16 + c;
        const bool same = (tj[nt] == ti);
        const bool vpos = same && (j != i);
        const float lp = (fminf(s, 1.25f) - 1.25f) * fmaf(s, 64.f, -48.f);
        const float sv = vpos ? lp : -2e30f;
        sel[nt] = sv;
        m = fmaxf(m, sv);
        const float ln = (fmaxf(s, -0.25f) + 0.25f) * fmaf(s, 64.f, -16.f);
        const float en = __expf(ln);
        sn += same ? 0.f : en;
      }
      #pragma unroll
      for (int off = 1; off < 16; off <<= 1) m = fmaxf(m, __shfl_xor(m, off));
      float sp = 0.f;
      #pragma unroll
      for (int nt = 0; nt < 4; ++nt) sp += __expf(sel[nt] - m);
      #pragma unroll
      for (int off = 1; off < 16; off <<= 1) {
        sp += __shfl_xor(sp, off);
        sn += __shfl_xor(sn, off);
      }
      if (c == 0) {
        float4 o; o.x = m; o.y = sp; o.z = 0.f; o.w = sn;
        partial[(size_t)i * nb + bj] = o;
      }
    }
  }

  // orientation 2: rows of bj block, cols of bi block (off-diagonal only)
  if (!isdiag) {
    #pragma unroll
    for (int nt = 0; nt < 4; ++nt) {
      const int jt = tj[nt];
      const int jrow = j0 + nt * 16 + c;
      float m = -1e30f, sn = 0.f;
      float sel[16];
      #pragma unroll
      for (int mt = 0; mt < 4; ++mt) {
        #pragma unroll
        for (int reg = 0; reg < 4; ++reg) {
          const float s = acc[mt][nt][reg];
          const bool same = (tir[mt * 4 + reg] == jt);  // j != i off-diagonal
          const float lp = (fminf(s, 1.25f) - 1.25f) * fmaf(s, 64.f, -48.f);
          const float sv = same ? lp : -2e30f;
          sel[mt * 4 + reg] = sv;
          m = fmaxf(m, sv);
          const float ln = (fmaxf(s, -0.25f) + 0.25f) * fmaf(s, 64.f, -16.f);
          const float en = __expf(ln);
          sn += same ? 0.f : en;
        }
      }
      m = fmaxf(m, __shfl_xor(m, 16));
      m = fmaxf(m, __shfl_xor(m, 32));
      float sp = 0.f;
      #pragma unroll
      for (int k = 0; k < 16; ++k) sp += __expf(sel[k] - m);
      sp += __shfl_xor(sp, 16); sp += __shfl_xor(sp, 32);
      sn += __shfl_xor(sn, 16); sn += __shfl_xor(sn, 32);
      if (lane < 16) {
        float4 o; o.x = m; o.y = sp; o.z = 0.f; o.w = sn;
        partial[(size_t)jrow * nb + bi] = o;
      }
    }
  }
}

// ---------------------------------------------------------------------------
// Kernel C: fold 128 partials per row -> row loss. One wave per row.
// ---------------------------------------------------------------------------
__global__ __launch_bounds__(THREADS) void k_reduce(const float4* __restrict__ partial,
                                                    float* __restrict__ row_loss) {
  const int lane = threadIdx.x & 63;
  const int row = blockIdx.x * 4 + (threadIdx.x >> 6);
  const float4 a = partial[(size_t)row * 128 + lane];
  const float4 b = partial[(size_t)row * 128 + 64 + lane];
  float mp = fmaxf(a.x, b.x);
  float sp = a.y * __expf(a.x - mp) + b.y * __expf(b.x - mp);
  float sn = a.w + b.w;
  #pragma unroll
  for (int off = 1; off < 64; off <<= 1) {
    const float m2 = __shfl_xor(mp, off), s2 = __shfl_xor(sp, off);
    const float nm = fmaxf(mp, m2);
    sp = sp * __expf(mp - nm) + s2 * __expf(m2 - nm);
    mp = nm;
    sn += __shfl_xor(sn, off);
  }
  if (lane == 0) {
    float loss = -1.0f;
    if (sp > 0.f && sn > 0.f) {
      const float z = mp + logf(sp) + logf(sn);
      loss = (z > 0.f) ? (z + log1pf(__expf(-z))) : log1pf(__expf(z));
    }
    row_loss[row] = loss;
  }
}

// ---------------------------------------------------------------------------
// Kernel D: masked mean over rows. One block.
// ---------------------------------------------------------------------------
__global__ __launch_bounds__(THREADS) void k_final(const float* __restrict__ row_loss,
                                                   float* __restrict__ out, int B) {
  __shared__ float ssum[4];
  __shared__ float scnt[4];
  const int tid = threadIdx.x;
  float sum = 0.f, cnt = 0.f;
  for (int i = tid; i < B; i += THREADS) {
    const float l = row_loss[i];
    if (l >= 0.f) { sum += l; cnt += 1.f; }
  }
  #pragma unroll
  for (int off = 32; off; off >>= 1) {
    sum += __shfl_xor(sum, off);
    cnt += __shfl_xor(cnt, off);
  }
  if ((tid & 63) == 0) { ssum[tid >> 6] = sum; scnt[tid >> 6] = cnt; }
  __syncthreads();
  if (tid == 0) {
    float ts = 0.f, tc = 0.f;
    #pragma unroll
    for (int w = 0; w < 4; ++w) { ts += ssum[w]; tc += scnt[w]; }
    out[0] = ts / fmaxf(tc, 1.f);
  }
}

// ---------------------------------------------------------------------------
extern "C" void kernel_launch(void* const* d_in, const int* in_sizes, int n_in,
                              void* d_out, int out_size, void* d_ws, size_t ws_size,
                              hipStream_t stream) {
  const float* x = (const float*)d_in[0];
  const int* tgt = (const int*)d_in[1];
  float* out = (float*)d_out;
  const int B = in_sizes[1];
  const int D = in_sizes[0] / B;
  const int nb = B / 64;                     // 128 wave-tile blocks of 64
  const int ntiles = nb * (nb + 1) / 2;      // 8256

  ushortT* xn = (ushortT*)d_ws;                                   // B*D bf16 (16 MB)
  float4* partial = (float4*)((char*)d_ws + (size_t)B * D * 2);   // B*nb float4 (16 MB)
  float* row_loss = (float*)((char*)d_ws + (size_t)B * D * 2 + (size_t)B * nb * 16);

  k_prep<<<B, THREADS, 0, stream>>>(x, xn, D);
  k_main_mfma<<<ntiles / 4, THREADS, 0, stream>>>(xn, tgt, partial, D, nb);
  k_reduce<<<B / 4, THREADS, 0, stream>>>(partial, row_loss);
  k_final<<<1, THREADS, 0, stream>>>(row_loss, out, B);
}

// Round 5
// 259.590 us; speedup vs baseline: 1.3742x; 1.3742x over previous
//
#include <hip/hip_runtime.h>
#include <hip/hip_bf16.h>
#include <math.h>

#define THREADS 256
typedef unsigned short ushortT;
typedef __attribute__((ext_vector_type(8))) short bf16x8;   // 8 bf16 = 4 VGPRs
typedef __attribute__((ext_vector_type(4))) float f32x4;

__device__ __forceinline__ void async16(const ushortT* g, ushortT* l) {
  __builtin_amdgcn_global_load_lds(
      (const __attribute__((address_space(1))) unsigned int*)g,
      (__attribute__((address_space(3))) unsigned int*)l, 16, 0, 0);
}

__device__ __forceinline__ ushortT f2bf(float f) {
  __hip_bfloat16 h = __float2bfloat16(f);
  return *reinterpret_cast<ushortT*>(&h);
}

// ---------------------------------------------------------------------------
// Kernel A: fused L2-norm + bf16 convert. One block per row (256 thr x float4).
// ---------------------------------------------------------------------------
__global__ __launch_bounds__(THREADS) void k_prep(const float* __restrict__ x,
                                                  ushortT* __restrict__ xn, int D) {
  __shared__ float red[4];
  const int row = blockIdx.x;
  const int tid = threadIdx.x;
  const int gid = row * (D / 4) + tid;
  const float4 v = reinterpret_cast<const float4*>(x)[gid];
  float s = v.x * v.x + v.y * v.y + v.z * v.z + v.w * v.w;
  #pragma unroll
  for (int off = 32; off; off >>= 1) s += __shfl_xor(s, off);
  if ((tid & 63) == 0) red[tid >> 6] = s;
  __syncthreads();
  const float tot = red[0] + red[1] + red[2] + red[3];
  const float rn = 1.0f / fmaxf(sqrtf(tot), 1e-12f);
  ushort4 o;
  o.x = f2bf(v.x * rn); o.y = f2bf(v.y * rn);
  o.z = f2bf(v.z * rn); o.w = f2bf(v.w * rn);
  reinterpret_cast<ushort4*>(xn)[gid] = o;
}

// ---------------------------------------------------------------------------
// Kernel B: triangular 128x128 bf16 MFMA tiles, DOUBLE-BUFFERED LDS staging.
// Per iter: issue async stage of k+1 into the other buffer BEFORE computing
// on the current buffer; barrier at iteration END so the structural vmcnt(0)
// drain lands after the prefetch has had the whole compute phase in flight.
// Staging layout is fragment-read order (lane*16B covers row=lane&15,
// chunk=lane>>4) -> ds_read_b128 conflict-free. __launch_bounds__(256,4)
// targets 4 blocks/CU so epilogue VALU overlaps other blocks' MFMA (m114).
// partial[(row*nb + cb)*2 + half] = {mp, sp, 0, sn}
// ---------------------------------------------------------------------------
__global__ __launch_bounds__(THREADS, 4) void k_main_mfma(const ushortT* __restrict__ xn,
                                                          const int* __restrict__ tgt,
                                                          float4* __restrict__ partial,
                                                          int D, int nb) {
  __shared__ ushortT Asm[2][128 * 32];  // 2 x 8 KB
  __shared__ ushortT Bsm[2][128 * 32];  // 2 x 8 KB

  const int tid = threadIdx.x;
  const int lane = tid & 63;
  const int w = tid >> 6;

  // --- triangular decode: b -> (bi, bj), bi <= bj
  const int b = blockIdx.x;
  int bi = (int)((2.f * nb + 1.f -
                  sqrtf((2.f * nb + 1.f) * (2.f * nb + 1.f) - 8.f * (float)b)) * 0.5f);
  while ((bi + 1) * (2 * nb - bi) / 2 <= b) ++bi;
  while (bi * (2 * nb - bi + 1) / 2 > b) --bi;
  const int bj = bi + (b - bi * (2 * nb - bi + 1) / 2);
  const bool isdiag = (bi == bj);

  const int i0 = bi * 128, j0 = bj * 128;
  const int wr = (w >> 1) * 64, wc = (w & 1) * 64;

  // --- staging: lane fetches (row = lane&15, chunk = lane>>4) of its group
  const int sr = lane & 15, sc = lane >> 4;
  const ushortT* gA0 = xn + (size_t)(i0 + w * 16 + sr) * D + sc * 8;
  const ushortT* gA1 = gA0 + (size_t)64 * D;
  const ushortT* gB0 = xn + (size_t)(j0 + w * 16 + sr) * D + sc * 8;
  const ushortT* gB1 = gB0 + (size_t)64 * D;
  const int lo0 = w * 512;        // ushort offset within a buffer
  const int lo1 = (w + 4) * 512;

  const int aoff = ((w >> 1) * 4) * 512 + lane * 8;   // ushort index
  const int boff = ((w & 1) * 4) * 512 + lane * 8;

  f32x4 acc[4][4];
  #pragma unroll
  for (int mt = 0; mt < 4; ++mt)
    #pragma unroll
    for (int nt = 0; nt < 4; ++nt)
      acc[mt][nt] = (f32x4){0.f, 0.f, 0.f, 0.f};

  // prologue: stage k=0 into buffer 0
  async16(gA0, &Asm[0][lo0]);
  async16(gA1, &Asm[0][lo1]);
  if (!isdiag) {
    async16(gB0, &Bsm[0][lo0]);
    async16(gB1, &Bsm[0][lo1]);
  }
  __syncthreads();

  const int kiters = D / 32;
  for (int kk = 0; kk < kiters; ++kk) {
    const int cur = kk & 1;
    if (kk + 1 < kiters) {   // stage next into other buffer BEFORE compute
      const size_t ko = (size_t)(kk + 1) * 32;
      async16(gA0 + ko, &Asm[cur ^ 1][lo0]);
      async16(gA1 + ko, &Asm[cur ^ 1][lo1]);
      if (!isdiag) {
        async16(gB0 + ko, &Bsm[cur ^ 1][lo0]);
        async16(gB1 + ko, &Bsm[cur ^ 1][lo1]);
      }
    }
    const ushortT* Ab = &Asm[cur][0];
    const ushortT* Bb = isdiag ? &Asm[cur][0] : &Bsm[cur][0];
    bf16x8 afr[4], bfr[4];
    #pragma unroll
    for (int mt = 0; mt < 4; ++mt)
      afr[mt] = *reinterpret_cast<const bf16x8*>(&Ab[aoff + mt * 512]);
    #pragma unroll
    for (int nt = 0; nt < 4; ++nt)
      bfr[nt] = *reinterpret_cast<const bf16x8*>(&Bb[boff + nt * 512]);
    #pragma unroll
    for (int mt = 0; mt < 4; ++mt)
      #pragma unroll
      for (int nt = 0; nt < 4; ++nt)
        acc[mt][nt] = __builtin_amdgcn_mfma_f32_16x16x32_bf16(afr[mt], bfr[nt], acc[mt][nt], 0, 0, 0);
    __syncthreads();   // seals buf[cur] reads; drains the kk+1 prefetch
  }

  // --- epilogue. C/D layout: col = lane&15, row = (lane>>4)*4 + reg
  const int q = lane >> 4, c = lane & 15;
  int tj[4];
  #pragma unroll
  for (int nt = 0; nt < 4; ++nt) tj[nt] = tgt[j0 + wc + nt * 16 + c];
  int tir[16];
  #pragma unroll
  for (int mt = 0; mt < 4; ++mt) {
    const int4 t4 = *reinterpret_cast<const int4*>(tgt + i0 + wr + mt * 16 + q * 4);
    tir[mt * 4 + 0] = t4.x; tir[mt * 4 + 1] = t4.y;
    tir[mt * 4 + 2] = t4.z; tir[mt * 4 + 3] = t4.w;
  }

  // orientation 1: rows of bi block, cols of bj block
  #pragma unroll
  for (int mt = 0; mt < 4; ++mt) {
    #pragma unroll
    for (int reg = 0; reg < 4; ++reg) {
      const int i = i0 + wr + mt * 16 + q * 4 + reg;
      const int ti = tir[mt * 4 + reg];
      float m = -1e30f, sn = 0.f;
      float sel[4];
      #pragma unroll
      for (int nt = 0; nt < 4; ++nt) {
        const float s = acc[mt][nt][reg];
        const int j = j0 + wc + nt * 16 + c;
        const bool same = (tj[nt] == ti);
        const bool vpos = same && (j != i);
        const float lp = (fminf(s, 1.25f) - 1.25f) * fmaf(s, 64.f, -48.f);
        const float sv = vpos ? lp : -2e30f;
        sel[nt] = sv;
        m = fmaxf(m, sv);
        const float ln = (fmaxf(s, -0.25f) + 0.25f) * fmaf(s, 64.f, -16.f);
        const float en = __expf(ln);
        sn += same ? 0.f : en;
      }
      #pragma unroll
      for (int off = 1; off < 16; off <<= 1) m = fmaxf(m, __shfl_xor(m, off));
      float sp = 0.f;
      #pragma unroll
      for (int nt = 0; nt < 4; ++nt) sp += __expf(sel[nt] - m);
      #pragma unroll
      for (int off = 1; off < 16; off <<= 1) {
        sp += __shfl_xor(sp, off);
        sn += __shfl_xor(sn, off);
      }
      if (c == 0) {
        float4 o; o.x = m; o.y = sp; o.z = 0.f; o.w = sn;
        partial[((size_t)i * nb + bj) * 2 + (w & 1)] = o;
      }
    }
  }

  // orientation 2: rows of bj block, cols of bi block (off-diagonal only)
  if (!isdiag) {
    #pragma unroll
    for (int nt = 0; nt < 4; ++nt) {
      const int jt = tj[nt];
      const int jrow = j0 + wc + nt * 16 + c;
      float m = -1e30f, sn = 0.f;
      float sel[16];
      #pragma unroll
      for (int mt = 0; mt < 4; ++mt) {
        #pragma unroll
        for (int reg = 0; reg < 4; ++reg) {
          const float s = acc[mt][nt][reg];
          const bool same = (tir[mt * 4 + reg] == jt);  // j != i off-diagonal
          const float lp = (fminf(s, 1.25f) - 1.25f) * fmaf(s, 64.f, -48.f);
          const float sv = same ? lp : -2e30f;
          sel[mt * 4 + reg] = sv;
          m = fmaxf(m, sv);
          const float ln = (fmaxf(s, -0.25f) + 0.25f) * fmaf(s, 64.f, -16.f);
          const float en = __expf(ln);
          sn += same ? 0.f : en;
        }
      }
      m = fmaxf(m, __shfl_xor(m, 16));
      m = fmaxf(m, __shfl_xor(m, 32));
      float sp = 0.f;
      #pragma unroll
      for (int k = 0; k < 16; ++k) sp += __expf(sel[k] - m);
      sp += __shfl_xor(sp, 16); sp += __shfl_xor(sp, 32);
      sn += __shfl_xor(sn, 16); sn += __shfl_xor(sn, 32);
      if (lane < 16) {
        float4 o; o.x = m; o.y = sp; o.z = 0.f; o.w = sn;
        partial[((size_t)jrow * nb + bi) * 2 + (w >> 1)] = o;
      }
    }
  }
}

// ---------------------------------------------------------------------------
// Kernel C: fold 128 partials per row -> row loss. One wave per row.
// ---------------------------------------------------------------------------
__global__ __launch_bounds__(THREADS) void k_reduce(const float4* __restrict__ partial,
                                                    float* __restrict__ row_loss) {
  const int lane = threadIdx.x & 63;
  const int row = blockIdx.x * 4 + (threadIdx.x >> 6);
  const float4 a = partial[(size_t)row * 128 + lane];
  const float4 b = partial[(size_t)row * 128 + 64 + lane];
  float mp = fmaxf(a.x, b.x);
  float sp = a.y * __expf(a.x - mp) + b.y * __expf(b.x - mp);
  float sn = a.w + b.w;
  #pragma unroll
  for (int off = 1; off < 64; off <<= 1) {
    const float m2 = __shfl_xor(mp, off), s2 = __shfl_xor(sp, off);
    const float nm = fmaxf(mp, m2);
    sp = sp * __expf(mp - nm) + s2 * __expf(m2 - nm);
    mp = nm;
    sn += __shfl_xor(sn, off);
  }
  if (lane == 0) {
    float loss = -1.0f;
    if (sp > 0.f && sn > 0.f) {
      const float z = mp + logf(sp) + logf(sn);
      loss = (z > 0.f) ? (z + log1pf(__expf(-z))) : log1pf(__expf(z));
    }
    row_loss[row] = loss;
  }
}

// ---------------------------------------------------------------------------
// Kernel D: masked mean over rows. One block.
// ---------------------------------------------------------------------------
__global__ __launch_bounds__(THREADS) void k_final(const float* __restrict__ row_loss,
                                                   float* __restrict__ out, int B) {
  __shared__ float ssum[4];
  __shared__ float scnt[4];
  const int tid = threadIdx.x;
  float sum = 0.f, cnt = 0.f;
  for (int i = tid; i < B; i += THREADS) {
    const float l = row_loss[i];
    if (l >= 0.f) { sum += l; cnt += 1.f; }
  }
  #pragma unroll
  for (int off = 32; off; off >>= 1) {
    sum += __shfl_xor(sum, off);
    cnt += __shfl_xor(cnt, off);
  }
  if ((tid & 63) == 0) { ssum[tid >> 6] = sum; scnt[tid >> 6] = cnt; }
  __syncthreads();
  if (tid == 0) {
    float ts = 0.f, tc = 0.f;
    #pragma unroll
    for (int w = 0; w < 4; ++w) { ts += ssum[w]; tc += scnt[w]; }
    out[0] = ts / fmaxf(tc, 1.f);
  }
}

// ---------------------------------------------------------------------------
extern "C" void kernel_launch(void* const* d_in, const int* in_sizes, int n_in,
                              void* d_out, int out_size, void* d_ws, size_t ws_size,
                              hipStream_t stream) {
  const float* x = (const float*)d_in[0];
  const int* tgt = (const int*)d_in[1];
  float* out = (float*)d_out;
  const int B = in_sizes[1];
  const int D = in_sizes[0] / B;
  const int nb = B / 128;

  ushortT* xn = (ushortT*)d_ws;                                   // B*D bf16 (16 MB)
  float4* partial = (float4*)((char*)d_ws + (size_t)B * D * 2);   // B*2*nb float4 (16 MB)
  float* row_loss = (float*)((char*)d_ws + (size_t)B * D * 2 + (size_t)B * 2 * nb * 16);

  k_prep<<<B, THREADS, 0, stream>>>(x, xn, D);
  k_main_mfma<<<nb * (nb + 1) / 2, THREADS, 0, stream>>>(xn, tgt, partial, D, nb);
  k_reduce<<<B / 4, THREADS, 0, stream>>>(partial, row_loss);
  k_final<<<1, THREADS, 0, stream>>>(row_loss, out, B);
}